// Round 4
// baseline (3746.896 us; speedup 1.0000x reference)
//
#include <hip/hip_runtime.h>
#include <math.h>

#define QLEN 512
#define NB   64
#define DD   128
#define HH   256
#define WOUT 64
#define PI_F 3.14159265358979323846f

__device__ __forceinline__ float sigmf(float x){ return 1.0f/(1.0f+expf(-x)); }
__device__ __forceinline__ float geluf(float x){ return 0.5f*x*(1.0f+erff(x*0.7071067811865476f)); }

// ---------------------------------------------------------------------------
// conv weights (O,I,K) -> (K,I,O) so inner GEMM reads are o-contiguous
__global__ void tconv_k(const float* __restrict__ in, float* __restrict__ out,
                        int O, int I, int K) {
    int idx = blockIdx.x*256 + threadIdx.x;
    if (idx >= O*I*K) return;
    int o = idx % O; int rest = idx / O; int i = rest % I; int k = rest / I;
    out[idx] = in[(o*I + i)*K + k];
}

// Rollout weight packing (fp32 MANDATORY — recurrence amplifies weight noise
// ~1e6x; bf16 weights fully decorrelated the output in round 2).
// WriS: slice layout for z-dot. slot idx: oo=idx&63; r=idx>>6; j=r%6; p=(r/6)%16; g=r/96.
// value = riw[o=g*64+oo][4*(p*6+j) .. +3]
__global__ void pack_wri_k(const float* __restrict__ riw, float4* __restrict__ out) {
    int idx = blockIdx.x*256 + threadIdx.x;
    if (idx >= 24576) return;
    int oo = idx & 63; int r = idx >> 6;
    int j = r % 6; r /= 6;
    int p = r % 16; int g = r / 16;
    int f4 = p*6 + j;
    int o  = g*64 + oo;
    const float* s = riw + (size_t)o*384 + 4*f4;
    float4 v; v.x=s[0]; v.y=s[1]; v.z=s[2]; v.w=s[3];
    out[idx] = v;
}
// WgS: slot idx: oo=idx&63; r=idx>>6; gate=r%6; j=(r/6)%4; p=(r/24)%16; g=r/384.
// gate<3: wih[(gate*256+o)][4*(p*4+j)..], else whh[((gate-3)*256+o)][...]
__global__ void pack_wg_k(const float* __restrict__ wih, const float* __restrict__ whh,
                          float4* __restrict__ out) {
    int idx = blockIdx.x*256 + threadIdx.x;
    if (idx >= 98304) return;
    int oo = idx & 63; int r = idx >> 6;
    int gate = r % 6; r /= 6;
    int j = r % 4; r /= 4;
    int p = r % 16; int g = r / 16;
    int j4 = p*4 + j;
    int o  = g*64 + oo;
    const float* s = (gate < 3) ? (wih + ((size_t)(gate*256 + o))*256 + 4*j4)
                                : (whh + ((size_t)((gate-3)*256 + o))*256 + 4*j4);
    float4 v; v.x=s[0]; v.y=s[1]; v.z=s[2]; v.w=s[3];
    out[idx] = v;
}

// ---------------------------------------------------------------------------
// Tiled conv-as-GEMM. X rows are (B,Q,CIN) time-major. Wt layout (KS,CIN,COUT).
template<int CIN, int COUT, int KS, int DIL, int ACT, int FEATS>
__global__ __launch_bounds__(256) void conv_gemm_k(
    const float* __restrict__ X, const float* __restrict__ Wt,
    const float* __restrict__ bias, float* __restrict__ Y)
{
    constexpr int TM   = 32;
    constexpr int HALO = (KS == 3) ? DIL : 0;
    constexpr int ROWS = TM + 2*HALO;
    constexpr int CPT  = COUT/64;
    __shared__ __align__(16) float As[ROWS*CIN];

    const int b  = blockIdx.y;
    const int t0 = blockIdx.x * TM;
    const int tid = threadIdx.x;

    if constexpr (FEATS) {
        for (int idx = tid; idx < TM*DD; idx += 256) {
            int r = idx >> 7, d = idx & (DD-1);
            int t = t0 + r;
            const float* xr = X + ((size_t)b*QLEN + t)*DD + d;
            float x    = xr[0];
            float xm1  = (t >= 1) ? xr[-DD]   : 0.f;
            float xm2  = (t >= 2) ? xr[-2*DD] : 0.f;
            float dy   = (t >= 1) ? (x - xm1)   : 0.f;
            float dym1 = (t >= 2) ? (xm1 - xm2) : 0.f;
            float ddy  = (t >= 1) ? (dy - dym1) : 0.f;
            As[r*CIN + d]        = x;
            As[r*CIN + DD + d]   = dy;
            As[r*CIN + 2*DD + d] = ddy;
        }
    } else {
        for (int idx = tid; idx < ROWS*(CIN/4); idx += 256) {
            int r = idx / (CIN/4), c4 = idx % (CIN/4);
            int gr = t0 + r - HALO;
            gr = gr < 0 ? 0 : (gr > QLEN-1 ? QLEN-1 : gr);
            float4 v = reinterpret_cast<const float4*>(X + ((size_t)b*QLEN + gr)*CIN)[c4];
            reinterpret_cast<float4*>(As)[r*(CIN/4) + c4] = v;
        }
    }
    __syncthreads();

    const int lane = tid & 63, rg = tid >> 6;
    const int c0 = lane * CPT;
    const int r0 = rg * 8;

    float acc[8][CPT];
    #pragma unroll
    for (int j = 0; j < 8; ++j)
        #pragma unroll
        for (int p = 0; p < CPT; ++p) acc[j][p] = 0.f;

    for (int k = 0; k < KS; ++k) {
        const float* Wk = Wt + (size_t)k*CIN*COUT + c0;
        for (int ci = 0; ci < CIN; ci += 4) {
            float w[4][CPT];
            #pragma unroll
            for (int q = 0; q < 4; ++q) {
                if constexpr (CPT == 4) {
                    float4 wv = *reinterpret_cast<const float4*>(Wk + (size_t)(ci+q)*COUT);
                    w[q][0]=wv.x; w[q][1]=wv.y; w[q][2]=wv.z; w[q][3]=wv.w;
                } else {
                    float2 wv = *reinterpret_cast<const float2*>(Wk + (size_t)(ci+q)*COUT);
                    w[q][0]=wv.x; w[q][1]=wv.y;
                }
            }
            #pragma unroll
            for (int j = 0; j < 8; ++j) {
                const float4 a = *reinterpret_cast<const float4*>(&As[(r0 + j + k*DIL)*CIN + ci]);
                #pragma unroll
                for (int p = 0; p < CPT; ++p) {
                    acc[j][p] = fmaf(a.x, w[0][p], acc[j][p]);
                    acc[j][p] = fmaf(a.y, w[1][p], acc[j][p]);
                    acc[j][p] = fmaf(a.z, w[2][p], acc[j][p]);
                    acc[j][p] = fmaf(a.w, w[3][p], acc[j][p]);
                }
            }
        }
    }

    float bv[CPT];
    #pragma unroll
    for (int p = 0; p < CPT; ++p) bv[p] = bias[c0 + p];

    #pragma unroll
    for (int j = 0; j < 8; ++j) {
        float o[CPT];
        #pragma unroll
        for (int p = 0; p < CPT; ++p) {
            float v = acc[j][p] + bv[p];
            if constexpr (ACT == 1) v = geluf(v);
            if constexpr (ACT == 2) v = sigmf(v);
            o[p] = v;
        }
        float* yr = Y + ((size_t)b*QLEN + t0 + r0 + j)*COUT + c0;
        if constexpr (CPT == 4) {
            float4 ov; ov.x=o[0]; ov.y=o[1]; ov.z=o[2]; ov.w=o[3];
            *reinterpret_cast<float4*>(yr) = ov;
        } else {
            float2 ov; ov.x=o[0]; ov.y=o[1];
            *reinterpret_cast<float2*>(yr) = ov;
        }
    }
}

// ---------------------------------------------------------------------------
// LayerNorm over H=256 channels per (b,t) row; optional residual add.
__global__ __launch_bounds__(256) void ln_k(
    const float* __restrict__ X, const float* __restrict__ R,
    const float* __restrict__ w, const float* __restrict__ b,
    float* __restrict__ Y)
{
    int row  = blockIdx.x*4 + (threadIdx.x >> 6);
    int lane = threadIdx.x & 63;
    float4 v = reinterpret_cast<const float4*>(X + (size_t)row*HH)[lane];
    if (R) {
        float4 rv = reinterpret_cast<const float4*>(R + (size_t)row*HH)[lane];
        v.x += rv.x; v.y += rv.y; v.z += rv.z; v.w += rv.w;
    }
    float s = v.x + v.y + v.z + v.w;
    #pragma unroll
    for (int off = 32; off > 0; off >>= 1) s += __shfl_xor(s, off);
    float m = s * (1.0f/HH);
    float dx=v.x-m, dy=v.y-m, dz=v.z-m, dw=v.w-m;
    float q = dx*dx + dy*dy + dz*dz + dw*dw;
    #pragma unroll
    for (int off = 32; off > 0; off >>= 1) q += __shfl_xor(q, off);
    float inv = rsqrtf(q*(1.0f/HH) + 1e-5f);
    float4 wv = reinterpret_cast<const float4*>(w)[lane];
    float4 bv = reinterpret_cast<const float4*>(b)[lane];
    float4 o;
    o.x = dx*inv*wv.x + bv.x;
    o.y = dy*inv*wv.y + bv.y;
    o.z = dz*inv*wv.z + bv.z;
    o.w = dw*inv*wv.w + bv.w;
    reinterpret_cast<float4*>(Y + (size_t)row*HH)[lane] = o;
}

// ---------------------------------------------------------------------------
__global__ __launch_bounds__(256) void rhophi_k(
    const float* __restrict__ Hs, const float* __restrict__ rpw,
    const float* __restrict__ rpb, float* __restrict__ rho, float* __restrict__ phi)
{
    int row  = blockIdx.x*4 + (threadIdx.x >> 6);
    int lane = threadIdx.x & 63;
    float4 h  = reinterpret_cast<const float4*>(Hs + (size_t)row*HH)[lane];
    float4 w0 = reinterpret_cast<const float4*>(rpw)[lane];
    float4 w1 = reinterpret_cast<const float4*>(rpw + HH)[lane];
    float d0 = h.x*w0.x + h.y*w0.y + h.z*w0.z + h.w*w0.w;
    float d1 = h.x*w1.x + h.y*w1.y + h.z*w1.z + h.w*w1.w;
    #pragma unroll
    for (int off = 32; off > 0; off >>= 1) { d0 += __shfl_xor(d0, off); d1 += __shfl_xor(d1, off); }
    if (lane == 0) {
        rho[row] = 1.25f * sigmf(d0 + rpb[0]);
        phi[row] = PI_F * tanhf(d1 + rpb[1]);
    }
}

// ---------------------------------------------------------------------------
__global__ __launch_bounds__(64) void kalman_k(
    const float* __restrict__ Xin, const float* __restrict__ Kg,
    const float* __restrict__ rho_a, const float* __restrict__ phi_a,
    float* __restrict__ xpost)
{
    int b = blockIdx.x, l = threadIdx.x;
    const float* xb = Xin + (size_t)b*QLEN*DD;
    float re = xb[l], im = xb[64 + l];
    for (int t = 0; t < QLEN; ++t) {
        float rho = rho_a[b*QLEN + t];
        float phi = phi_a[b*QLEN + t];
        float s, c; sincosf(phi, &s, &c);
        float pr = rho*(c*re - s*im);
        float pi = rho*(s*re + c*im);
        const float* kg = Kg + ((size_t)b*QLEN + t)*DD;
        const float* yr = xb + (size_t)t*DD;
        float kr = kg[l], ki = kg[64 + l];
        float y0 = yr[l], y1 = yr[64 + l];
        re = pr + kr*(y0 - pr);
        im = pi + ki*(y1 - pi);
    }
    xpost[b*DD + l]      = re;
    xpost[b*DD + 64 + l] = im;
}

// ---------------------------------------------------------------------------
// Rollout v4: 4 blocks per batch (o-sliced), 1024 threads each; 256 blocks
// total = 4096 waves, all co-resident (<= 8192 wave capacity) => the 2
// agent-scope flag syncs per step between a batch's 4 blocks cannot deadlock.
// Per-CU weight stream drops 1.97 MB -> 490 KB per step (the round-3
// bottleneck: 83% of per-CU L2 BW). fp32 everywhere (precision-mandatory).
__device__ __forceinline__ float bsum16(float v, float* red) {
    #pragma unroll
    for (int off = 32; off > 0; off >>= 1) v += __shfl_xor(v, off);
    __syncthreads();
    if ((threadIdx.x & 63) == 0) red[threadIdx.x >> 6] = v;
    __syncthreads();
    float s = 0.f;
    #pragma unroll
    for (int i = 0; i < 16; ++i) s += red[i];
    return s;
}

__device__ __forceinline__ void group_sync(int* flags, int base, int g, int seq) {
    __syncthreads();                    // all waves done with their phase work
    if (threadIdx.x == 0) {
        __threadfence();                // drain + make prior stores agent-visible
        __hip_atomic_store(&flags[base + g], seq, __ATOMIC_RELEASE,
                           __HIP_MEMORY_SCOPE_AGENT);
    }
    if (threadIdx.x < 4) {
        while (__hip_atomic_load(&flags[base + (int)threadIdx.x], __ATOMIC_ACQUIRE,
                                 __HIP_MEMORY_SCOPE_AGENT) < seq)
            __builtin_amdgcn_s_sleep(2);
    }
    __syncthreads();
}

__global__ __launch_bounds__(1024) void rollout_k4(
    const float* __restrict__ Hs, const float* __restrict__ xpost,
    const float4* __restrict__ WriS, const float* __restrict__ rib,
    const float4* __restrict__ WgS,
    const float* __restrict__ bih, const float* __restrict__ bhh,
    const float* __restrict__ lnw, const float* __restrict__ lnb,
    const float* __restrict__ rpw, const float* __restrict__ rpb,
    float* __restrict__ zbuf, float* __restrict__ gobuf, int* __restrict__ flags,
    float* __restrict__ out)
{
    __shared__ __align__(16) float hcf[384];   // h_r[0:256) ++ curr[256:384)
    __shared__ __align__(16) float zf[256];    // full z
    __shared__ __align__(16) float gof[256];   // full GRU output
    __shared__ float zp[16*64];                // z partials [p][oo]
    __shared__ float gp[6][16][64];            // gate partials [gate][p][oo]
    __shared__ float red[16];

    const int tid = threadIdx.x;
    const int p = tid >> 6, oo = tid & 63;
    const int b = blockIdx.x & 63, g = blockIdx.x >> 6;   // stride-64 grouping:
    // batch b's 4 blocks are {b, b+64, b+128, b+192} -> same XCD under %8
    // round-robin dispatch (perf heuristic only, correctness independent).
    const int o = g*64 + oo;
    const int fbase = b*4;

    if (tid < HH)            hcf[tid]      = Hs[((size_t)b*QLEN + QLEN-1)*HH + tid];
    else if (tid < HH+DD)    hcf[tid]      = xpost[b*DD + (tid-HH)];

    const float bi0 = bih[o],  bi1 = bih[HH+o], bi2 = bih[2*HH+o];
    const float bh0 = bhh[o],  bh1 = bhh[HH+o], bh2 = bhh[2*HH+o];
    const float rb  = rib[o];
    const int   t8  = tid & 255;
    const float lw  = lnw[t8], lb = lnb[t8];
    const float rw0 = rpw[t8], rw1 = rpw[HH+t8];
    const float rpb0 = rpb[0], rpb1 = rpb[1];
    const float4* hcf4 = reinterpret_cast<const float4*>(hcf);
    const float4* zf4  = reinterpret_cast<const float4*>(zf);
    __syncthreads();

    for (int s = 0; s < WOUT; ++s) {
        // ---- z partials: 384-dot split 16 ways (24 dims each)
        float az = 0.f;
        {
            const float4* wp = WriS + ((size_t)(g*16 + p)*6)*64 + oo;
            #pragma unroll
            for (int j = 0; j < 6; ++j) {
                float4 w = wp[(size_t)j*64];
                float4 h = hcf4[p*6 + j];
                az = fmaf(w.x,h.x,az); az = fmaf(w.y,h.y,az);
                az = fmaf(w.z,h.z,az); az = fmaf(w.w,h.w,az);
            }
        }
        zp[p*64 + oo] = az;
        __syncthreads();
        if (p == 0) {
            float zv = rb;
            #pragma unroll
            for (int q = 0; q < 16; ++q) zv += zp[q*64 + oo];
            __hip_atomic_store(&zbuf[b*HH + o], tanhf(zv), __ATOMIC_RELAXED,
                               __HIP_MEMORY_SCOPE_AGENT);
        }
        group_sync(flags, fbase, g, 2*s + 1);
        if (tid < HH)
            zf[tid] = __hip_atomic_load(&zbuf[b*HH + tid], __ATOMIC_RELAXED,
                                        __HIP_MEMORY_SCOPE_AGENT);
        __syncthreads();

        // ---- gate partials: 6 dots of 256 split 16 ways (16 dims each)
        float g0=0.f,g1=0.f,g2=0.f,e0=0.f,e1=0.f,e2=0.f;
        {
            const float4* wb0 = WgS + ((size_t)((g*16 + p)*4)*6)*64 + oo;
            #pragma unroll
            for (int j = 0; j < 4; ++j) {
                const float4* wj = wb0 + (size_t)j*6*64;
                float4 z = zf4[p*4 + j];
                float4 h = hcf4[p*4 + j];
                float4 wa = wj[0], wbv = wj[64], wc = wj[128];
                float4 wd = wj[192], we = wj[256], wf = wj[320];
                g0 = fmaf(wa.x,z.x,g0); g0 = fmaf(wa.y,z.y,g0); g0 = fmaf(wa.z,z.z,g0); g0 = fmaf(wa.w,z.w,g0);
                g1 = fmaf(wbv.x,z.x,g1); g1 = fmaf(wbv.y,z.y,g1); g1 = fmaf(wbv.z,z.z,g1); g1 = fmaf(wbv.w,z.w,g1);
                g2 = fmaf(wc.x,z.x,g2); g2 = fmaf(wc.y,z.y,g2); g2 = fmaf(wc.z,z.z,g2); g2 = fmaf(wc.w,z.w,g2);
                e0 = fmaf(wd.x,h.x,e0); e0 = fmaf(wd.y,h.y,e0); e0 = fmaf(wd.z,h.z,e0); e0 = fmaf(wd.w,h.w,e0);
                e1 = fmaf(we.x,h.x,e1); e1 = fmaf(we.y,h.y,e1); e1 = fmaf(we.z,h.z,e1); e1 = fmaf(we.w,h.w,e1);
                e2 = fmaf(wf.x,h.x,e2); e2 = fmaf(wf.y,h.y,e2); e2 = fmaf(wf.z,h.z,e2); e2 = fmaf(wf.w,h.w,e2);
            }
        }
        gp[0][p][oo]=g0; gp[1][p][oo]=g1; gp[2][p][oo]=g2;
        gp[3][p][oo]=e0; gp[4][p][oo]=e1; gp[5][p][oo]=e2;
        __syncthreads();
        if (p == 0) {
            float G0=bi0,G1=bi1,G2=bi2,E0=bh0,E1=bh1,E2=bh2;
            #pragma unroll
            for (int q = 0; q < 16; ++q) {
                G0 += gp[0][q][oo]; G1 += gp[1][q][oo]; G2 += gp[2][q][oo];
                E0 += gp[3][q][oo]; E1 += gp[4][q][oo]; E2 += gp[5][q][oo];
            }
            float r  = sigmf(G0 + E0);
            float zg = sigmf(G1 + E1);
            float n  = tanhf(G2 + r*E2);
            float go = (1.0f - zg)*n + zg*hcf[o];
            __hip_atomic_store(&gobuf[b*HH + o], go, __ATOMIC_RELAXED,
                               __HIP_MEMORY_SCOPE_AGENT);
        }
        group_sync(flags, fbase, g, 2*s + 2);
        if (tid < HH)
            gof[tid] = __hip_atomic_load(&gobuf[b*HH + tid], __ATOMIC_RELAXED,
                                         __HIP_MEMORY_SCOPE_AGENT);
        __syncthreads();

        // ---- LN over 256 (two-pass, matches reference) — redundant per block
        float vgo = (tid < HH) ? gof[tid] : 0.f;
        float m   = bsum16(vgo, red) * (1.0f/HH);
        float d   = (tid < HH) ? (vgo - m) : 0.f;
        float var = bsum16(d*d, red) * (1.0f/HH);
        float hn  = d * rsqrtf(var + 1e-5f) * lw + lb;
        float p0s = bsum16((tid < HH) ? hn*rw0 : 0.f, red);
        float p1s = bsum16((tid < HH) ? hn*rw1 : 0.f, red);
        float rho = 1.25f * sigmf(p0s + rpb0);
        float phi = PI_F * tanhf(p1s + rpb1);
        float sn, cs; sincosf(phi, &sn, &cs);

        if (tid < HH) hcf[tid] = hn;
        if (tid < 64) {
            float cre = hcf[HH + tid], cim = hcf[HH + 64 + tid];
            float nr = rho*(cs*cre - sn*cim);
            float ni = rho*(sn*cre + cs*cim);
            hcf[HH + tid] = nr; hcf[HH + 64 + tid] = ni;
            if (g == 0) {
                float* ob = out + ((size_t)b*WOUT + s)*DD;
                ob[tid] = nr; ob[64 + tid] = ni;
            }
        }
        __syncthreads();
    }
}

// ---------------------------------------------------------------------------
extern "C" void kernel_launch(void* const* d_in, const int* in_sizes, int n_in,
                              void* d_out, int out_size, void* d_ws, size_t ws_size,
                              hipStream_t stream)
{
    const float* x_in   = (const float*)d_in[0];
    const float* inp_w  = (const float*)d_in[2];
    const float* inp_b  = (const float*)d_in[3];
    const float* b0c1w  = (const float*)d_in[4];
    const float* b0c1b  = (const float*)d_in[5];
    const float* b0c2w  = (const float*)d_in[6];
    const float* b0c2b  = (const float*)d_in[7];
    const float* b0lnw  = (const float*)d_in[8];
    const float* b0lnb  = (const float*)d_in[9];
    const float* b1c1w  = (const float*)d_in[10];
    const float* b1c1b  = (const float*)d_in[11];
    const float* b1c2w  = (const float*)d_in[12];
    const float* b1c2b  = (const float*)d_in[13];
    const float* b1lnw  = (const float*)d_in[14];
    const float* b1lnb  = (const float*)d_in[15];
    const float* olnw   = (const float*)d_in[16];
    const float* olnb   = (const float*)d_in[17];
    const float* gainw  = (const float*)d_in[18];
    const float* gainb  = (const float*)d_in[19];
    const float* rpw    = (const float*)d_in[20];
    const float* rpb    = (const float*)d_in[21];
    const float* riw    = (const float*)d_in[22];
    const float* rib    = (const float*)d_in[23];
    const float* wih    = (const float*)d_in[24];
    const float* whh    = (const float*)d_in[25];
    const float* bih    = (const float*)d_in[26];
    const float* bhh    = (const float*)d_in[27];
    const float* rlnw   = (const float*)d_in[28];
    const float* rlnb   = (const float*)d_in[29];
    const float* rprw   = (const float*)d_in[30];
    const float* rprb   = (const float*)d_in[31];
    float* out = (float*)d_out;

    // workspace layout (floats)
    float* ws   = (float*)d_ws;
    float* buf0 = ws;                    // 8388608
    float* buf1 = ws +  8388608;         // 8388608
    float* buf2 = ws + 16777216;         // 8388608
    float* Kg    = buf2;                 // 4194304 (buf2 dead by then)
    float* rhoA  = buf2 + 4194304;       // 32768
    float* phiA  = rhoA + 32768;         // 32768
    float* xpost = phiA + 32768;         // 8192
    float* wts   = ws + 25165824;
    float* Wt_inp  = wts;                //  98304
    float* Wt_b0c1 = wts +   98304;      // 196608
    float* Wt_b0c2 = wts +  294912;      // 196608
    float* Wt_b1c1 = wts +  491520;      // 196608
    float* Wt_b1c2 = wts +  688128;      // 196608
    float* Wt_gain = wts +  884736;      //  32768
    float4* WriS   = (float4*)(wts +  917504);   // 24576 float4 =  98304 floats
    float4* WgS    = (float4*)(wts + 1015808);   // 98304 float4 = 393216 floats
    // total ws use: 26574848 floats ~= 101.4 MB (same as rounds 1-3)
    // rollout exchange buffers live in buf0 (dead after the final ln_k):
    float* zbuf  = buf0;                         // 16384 floats
    float* gobuf = buf0 + 16384;                 // 16384 floats
    int*   flags = (int*)(buf0 + 32768);         // 256 ints

    // ---- weight prep
    tconv_k<<<(98304+255)/256, 256, 0, stream>>>(inp_w, Wt_inp, 256, 384, 1);
    tconv_k<<<(196608+255)/256, 256, 0, stream>>>(b0c1w, Wt_b0c1, 256, 256, 3);
    tconv_k<<<(196608+255)/256, 256, 0, stream>>>(b0c2w, Wt_b0c2, 256, 256, 3);
    tconv_k<<<(196608+255)/256, 256, 0, stream>>>(b1c1w, Wt_b1c1, 256, 256, 3);
    tconv_k<<<(196608+255)/256, 256, 0, stream>>>(b1c2w, Wt_b1c2, 256, 256, 3);
    tconv_k<<<(32768+255)/256, 256, 0, stream>>>(gainw, Wt_gain, 128, 256, 1);
    pack_wri_k<<<(24576+255)/256, 256, 0, stream>>>(riw, WriS);
    pack_wg_k<<<(98304+255)/256, 256, 0, stream>>>(wih, whh, WgS);

    dim3 cg(QLEN/32, NB);

    // ---- input projection (feats built on the fly): x_in -> buf0
    conv_gemm_k<384,256,1,1,0,1><<<cg, 256, 0, stream>>>(x_in, Wt_inp, inp_b, buf0);

    // ---- block 0 (dil=1)
    conv_gemm_k<256,256,3,1,1,0><<<cg, 256, 0, stream>>>(buf0, Wt_b0c1, b0c1b, buf1);
    conv_gemm_k<256,256,3,1,1,0><<<cg, 256, 0, stream>>>(buf1, Wt_b0c2, b0c2b, buf2);
    ln_k<<<NB*QLEN/4, 256, 0, stream>>>(buf0, buf2, b0lnw, b0lnb, buf1);

    // ---- block 1 (dil=2)
    conv_gemm_k<256,256,3,2,1,0><<<cg, 256, 0, stream>>>(buf1, Wt_b1c1, b1c1b, buf0);
    conv_gemm_k<256,256,3,2,1,0><<<cg, 256, 0, stream>>>(buf0, Wt_b1c2, b1c2b, buf2);
    ln_k<<<NB*QLEN/4, 256, 0, stream>>>(buf1, buf2, b1lnw, b1lnb, buf0);

    // ---- output LN: h_seq -> buf1 (last read of buf0)
    ln_k<<<NB*QLEN/4, 256, 0, stream>>>(buf0, nullptr, olnw, olnb, buf1);

    // buf0 now dead -> clear the rollout sync flags (stream-ordered, capture-safe)
    hipMemsetAsync(flags, 0, 256*sizeof(int), stream);

    // ---- Kalman precompute: Kg (sigmoid GEMM), rho/phi
    conv_gemm_k<256,128,1,1,2,0><<<cg, 256, 0, stream>>>(buf1, Wt_gain, gainb, Kg);
    rhophi_k<<<NB*QLEN/4, 256, 0, stream>>>(buf1, rpw, rpb, rhoA, phiA);

    // ---- Kalman scan
    kalman_k<<<NB, 64, 0, stream>>>(x_in, Kg, rhoA, phiA, xpost);

    // ---- rollout v4: 4 o-sliced blocks per batch
    rollout_k4<<<4*NB, 1024, 0, stream>>>(buf1, xpost, WriS, rib, WgS,
                                          bih, bhh, rlnw, rlnb, rprw, rprb,
                                          zbuf, gobuf, flags, out);
}

// Round 5
// 2363.272 us; speedup vs baseline: 1.5855x; 1.5855x over previous
//
#include <hip/hip_runtime.h>
#include <math.h>

#define QLEN 512
#define NB   64
#define DD   128
#define HH   256
#define WOUT 64
#define PI_F 3.14159265358979323846f

__device__ __forceinline__ float sigmf(float x){ return 1.0f/(1.0f+expf(-x)); }
__device__ __forceinline__ float geluf(float x){ return 0.5f*x*(1.0f+erff(x*0.7071067811865476f)); }

// ---------------------------------------------------------------------------
// conv weights (O,I,K) -> (K,I,O) so inner GEMM reads are o-contiguous
__global__ void tconv_k(const float* __restrict__ in, float* __restrict__ out,
                        int O, int I, int K) {
    int idx = blockIdx.x*256 + threadIdx.x;
    if (idx >= O*I*K) return;
    int o = idx % O; int rest = idx / O; int i = rest % I; int k = rest / I;
    out[idx] = in[(o*I + i)*K + k];
}

// (R,C) row-major -> j-quad packed float4: out[j4*R + r] = in[r][4j4..4j4+3]
// NOTE: fp32 on purpose — the recurrent rollout amplifies weight noise ~1e6x;
// bf16 weights decorrelated the output entirely (round-2 absmax 31).
__global__ void pack_quads_k(const float* __restrict__ in, float4* __restrict__ out,
                             int R, int C) {
    int idx = blockIdx.x*256 + threadIdx.x;
    if (idx >= R*(C/4)) return;
    int r = idx % R, j4 = idx / R;
    const float* p = in + (size_t)r*C + 4*j4;
    float4 v; v.x = p[0]; v.y = p[1]; v.z = p[2]; v.w = p[3];
    out[idx] = v;
}

// ---------------------------------------------------------------------------
// Conv-as-GEMM, TM=32 variant (input projection w/ on-the-fly feats, and the
// small Kg GEMM). X rows are (B,Q,CIN) time-major. Wt layout (KS,CIN,COUT).
template<int CIN, int COUT, int KS, int DIL, int ACT, int FEATS>
__global__ __launch_bounds__(256) void conv_gemm_k(
    const float* __restrict__ X, const float* __restrict__ Wt,
    const float* __restrict__ bias, float* __restrict__ Y)
{
    constexpr int TM   = 32;
    constexpr int HALO = (KS == 3) ? DIL : 0;
    constexpr int ROWS = TM + 2*HALO;
    constexpr int CPT  = COUT/64;
    __shared__ __align__(16) float As[ROWS*CIN];

    const int b  = blockIdx.y;
    const int t0 = blockIdx.x * TM;
    const int tid = threadIdx.x;

    if constexpr (FEATS) {
        for (int idx = tid; idx < TM*DD; idx += 256) {
            int r = idx >> 7, d = idx & (DD-1);
            int t = t0 + r;
            const float* xr = X + ((size_t)b*QLEN + t)*DD + d;
            float x    = xr[0];
            float xm1  = (t >= 1) ? xr[-DD]   : 0.f;
            float xm2  = (t >= 2) ? xr[-2*DD] : 0.f;
            float dy   = (t >= 1) ? (x - xm1)   : 0.f;
            float dym1 = (t >= 2) ? (xm1 - xm2) : 0.f;
            float ddy  = (t >= 1) ? (dy - dym1) : 0.f;
            As[r*CIN + d]        = x;
            As[r*CIN + DD + d]   = dy;
            As[r*CIN + 2*DD + d] = ddy;
        }
    } else {
        for (int idx = tid; idx < ROWS*(CIN/4); idx += 256) {
            int r = idx / (CIN/4), c4 = idx % (CIN/4);
            int gr = t0 + r - HALO;
            gr = gr < 0 ? 0 : (gr > QLEN-1 ? QLEN-1 : gr);
            float4 v = reinterpret_cast<const float4*>(X + ((size_t)b*QLEN + gr)*CIN)[c4];
            reinterpret_cast<float4*>(As)[r*(CIN/4) + c4] = v;
        }
    }
    __syncthreads();

    const int lane = tid & 63, rg = tid >> 6;
    const int c0 = lane * CPT;
    const int r0 = rg * 8;

    float acc[8][CPT];
    #pragma unroll
    for (int j = 0; j < 8; ++j)
        #pragma unroll
        for (int p = 0; p < CPT; ++p) acc[j][p] = 0.f;

    for (int k = 0; k < KS; ++k) {
        const float* Wk = Wt + (size_t)k*CIN*COUT + c0;
        for (int ci = 0; ci < CIN; ci += 4) {
            float w[4][CPT];
            #pragma unroll
            for (int q = 0; q < 4; ++q) {
                if constexpr (CPT == 4) {
                    float4 wv = *reinterpret_cast<const float4*>(Wk + (size_t)(ci+q)*COUT);
                    w[q][0]=wv.x; w[q][1]=wv.y; w[q][2]=wv.z; w[q][3]=wv.w;
                } else {
                    float2 wv = *reinterpret_cast<const float2*>(Wk + (size_t)(ci+q)*COUT);
                    w[q][0]=wv.x; w[q][1]=wv.y;
                }
            }
            #pragma unroll
            for (int j = 0; j < 8; ++j) {
                const float4 a = *reinterpret_cast<const float4*>(&As[(r0 + j + k*DIL)*CIN + ci]);
                #pragma unroll
                for (int p = 0; p < CPT; ++p) {
                    acc[j][p] = fmaf(a.x, w[0][p], acc[j][p]);
                    acc[j][p] = fmaf(a.y, w[1][p], acc[j][p]);
                    acc[j][p] = fmaf(a.z, w[2][p], acc[j][p]);
                    acc[j][p] = fmaf(a.w, w[3][p], acc[j][p]);
                }
            }
        }
    }

    float bv[CPT];
    #pragma unroll
    for (int p = 0; p < CPT; ++p) bv[p] = bias[c0 + p];

    #pragma unroll
    for (int j = 0; j < 8; ++j) {
        float o[CPT];
        #pragma unroll
        for (int p = 0; p < CPT; ++p) {
            float v = acc[j][p] + bv[p];
            if constexpr (ACT == 1) v = geluf(v);
            if constexpr (ACT == 2) v = sigmf(v);
            o[p] = v;
        }
        float* yr = Y + ((size_t)b*QLEN + t0 + r0 + j)*COUT + c0;
        if constexpr (CPT == 4) {
            float4 ov; ov.x=o[0]; ov.y=o[1]; ov.z=o[2]; ov.w=o[3];
            *reinterpret_cast<float4*>(yr) = ov;
        } else {
            float2 ov; ov.x=o[0]; ov.y=o[1];
            *reinterpret_cast<float2*>(yr) = ov;
        }
    }
}

// ---------------------------------------------------------------------------
// Conv-as-GEMM, TM=64 variant for the 4 big dilated convs: 16 rows/wave
// halves per-FLOP L2 weight traffic vs TM=32 (weights re-streamed per wave)
// and gives 512 FMA-cyc per 16 LDS reads + 4 global loads.
template<int CIN, int COUT, int KS, int DIL, int ACT>
__global__ __launch_bounds__(256) void conv64_k(
    const float* __restrict__ X, const float* __restrict__ Wt,
    const float* __restrict__ bias, float* __restrict__ Y)
{
    constexpr int TM   = 64;
    constexpr int HALO = DIL;
    constexpr int ROWS = TM + 2*HALO;
    constexpr int CPT  = COUT/64;
    __shared__ __align__(16) float As[ROWS*CIN];   // dil2: 68*256*4 = 69.6 KB

    const int b  = blockIdx.y;
    const int t0 = blockIdx.x * TM;
    const int tid = threadIdx.x;

    for (int idx = tid; idx < ROWS*(CIN/4); idx += 256) {
        int r = idx / (CIN/4), c4 = idx % (CIN/4);
        int gr = t0 + r - HALO;
        gr = gr < 0 ? 0 : (gr > QLEN-1 ? QLEN-1 : gr);   // edge padding
        float4 v = reinterpret_cast<const float4*>(X + ((size_t)b*QLEN + gr)*CIN)[c4];
        reinterpret_cast<float4*>(As)[r*(CIN/4) + c4] = v;
    }
    __syncthreads();

    const int lane = tid & 63, rg = tid >> 6;
    const int c0 = lane * CPT;
    const int r0 = rg * 16;

    float acc[16][CPT];
    #pragma unroll
    for (int j = 0; j < 16; ++j)
        #pragma unroll
        for (int p = 0; p < CPT; ++p) acc[j][p] = 0.f;

    for (int k = 0; k < KS; ++k) {
        const float* Wk = Wt + (size_t)k*CIN*COUT + c0;
        #pragma unroll 2
        for (int ci = 0; ci < CIN; ci += 4) {
            float w[4][CPT];
            #pragma unroll
            for (int q = 0; q < 4; ++q) {
                float4 wv = *reinterpret_cast<const float4*>(Wk + (size_t)(ci+q)*COUT);
                w[q][0]=wv.x; w[q][1]=wv.y; w[q][2]=wv.z; w[q][3]=wv.w;
            }
            #pragma unroll
            for (int j = 0; j < 16; ++j) {
                const float4 a = *reinterpret_cast<const float4*>(&As[(r0 + j + k*DIL)*CIN + ci]);
                #pragma unroll
                for (int p = 0; p < CPT; ++p) {
                    acc[j][p] = fmaf(a.x, w[0][p], acc[j][p]);
                    acc[j][p] = fmaf(a.y, w[1][p], acc[j][p]);
                    acc[j][p] = fmaf(a.z, w[2][p], acc[j][p]);
                    acc[j][p] = fmaf(a.w, w[3][p], acc[j][p]);
                }
            }
        }
    }

    float bv[CPT];
    #pragma unroll
    for (int p = 0; p < CPT; ++p) bv[p] = bias[c0 + p];

    #pragma unroll
    for (int j = 0; j < 16; ++j) {
        float o[CPT];
        #pragma unroll
        for (int p = 0; p < CPT; ++p) {
            float v = acc[j][p] + bv[p];
            if constexpr (ACT == 1) v = geluf(v);
            if constexpr (ACT == 2) v = sigmf(v);
            o[p] = v;
        }
        float* yr = Y + ((size_t)b*QLEN + t0 + r0 + j)*COUT + c0;
        float4 ov; ov.x=o[0]; ov.y=o[1]; ov.z=o[2]; ov.w=o[3];
        *reinterpret_cast<float4*>(yr) = ov;
    }
}

// ---------------------------------------------------------------------------
// LayerNorm over H=256 channels per (b,t) row; optional residual add.
__global__ __launch_bounds__(256) void ln_k(
    const float* __restrict__ X, const float* __restrict__ R,
    const float* __restrict__ w, const float* __restrict__ b,
    float* __restrict__ Y)
{
    int row  = blockIdx.x*4 + (threadIdx.x >> 6);
    int lane = threadIdx.x & 63;
    float4 v = reinterpret_cast<const float4*>(X + (size_t)row*HH)[lane];
    if (R) {
        float4 rv = reinterpret_cast<const float4*>(R + (size_t)row*HH)[lane];
        v.x += rv.x; v.y += rv.y; v.z += rv.z; v.w += rv.w;
    }
    float s = v.x + v.y + v.z + v.w;
    #pragma unroll
    for (int off = 32; off > 0; off >>= 1) s += __shfl_xor(s, off);
    float m = s * (1.0f/HH);
    float dx=v.x-m, dy=v.y-m, dz=v.z-m, dw=v.w-m;
    float q = dx*dx + dy*dy + dz*dz + dw*dw;
    #pragma unroll
    for (int off = 32; off > 0; off >>= 1) q += __shfl_xor(q, off);
    float inv = rsqrtf(q*(1.0f/HH) + 1e-5f);
    float4 wv = reinterpret_cast<const float4*>(w)[lane];
    float4 bv = reinterpret_cast<const float4*>(b)[lane];
    float4 o;
    o.x = dx*inv*wv.x + bv.x;
    o.y = dy*inv*wv.y + bv.y;
    o.z = dz*inv*wv.z + bv.z;
    o.w = dw*inv*wv.w + bv.w;
    reinterpret_cast<float4*>(Y + (size_t)row*HH)[lane] = o;
}

// ---------------------------------------------------------------------------
__global__ __launch_bounds__(256) void rhophi_k(
    const float* __restrict__ Hs, const float* __restrict__ rpw,
    const float* __restrict__ rpb, float* __restrict__ rho, float* __restrict__ phi)
{
    int row  = blockIdx.x*4 + (threadIdx.x >> 6);
    int lane = threadIdx.x & 63;
    float4 h  = reinterpret_cast<const float4*>(Hs + (size_t)row*HH)[lane];
    float4 w0 = reinterpret_cast<const float4*>(rpw)[lane];
    float4 w1 = reinterpret_cast<const float4*>(rpw + HH)[lane];
    float d0 = h.x*w0.x + h.y*w0.y + h.z*w0.z + h.w*w0.w;
    float d1 = h.x*w1.x + h.y*w1.y + h.z*w1.z + h.w*w1.w;
    #pragma unroll
    for (int off = 32; off > 0; off >>= 1) { d0 += __shfl_xor(d0, off); d1 += __shfl_xor(d1, off); }
    if (lane == 0) {
        rho[row] = 1.25f * sigmf(d0 + rpb[0]);
        phi[row] = PI_F * tanhf(d1 + rpb[1]);
    }
}

// ---------------------------------------------------------------------------
__global__ __launch_bounds__(64) void kalman_k(
    const float* __restrict__ Xin, const float* __restrict__ Kg,
    const float* __restrict__ rho_a, const float* __restrict__ phi_a,
    float* __restrict__ xpost)
{
    int b = blockIdx.x, l = threadIdx.x;
    const float* xb = Xin + (size_t)b*QLEN*DD;
    float re = xb[l], im = xb[64 + l];
    for (int t = 0; t < QLEN; ++t) {
        float rho = rho_a[b*QLEN + t];
        float phi = phi_a[b*QLEN + t];
        float s, c; sincosf(phi, &s, &c);
        float pr = rho*(c*re - s*im);
        float pi = rho*(s*re + c*im);
        const float* kg = Kg + ((size_t)b*QLEN + t)*DD;
        const float* yr = xb + (size_t)t*DD;
        float kr = kg[l], ki = kg[64 + l];
        float y0 = yr[l], y1 = yr[64 + l];
        re = pr + kr*(y0 - pr);
        im = pi + ki*(y1 - pi);
    }
    xpost[b*DD + l]      = re;
    xpost[b*DD + 64 + l] = im;
}

// ---------------------------------------------------------------------------
// Rollout v3 (round-3 proven): 1024 threads/block, one block/batch, fp32
// weights, split-4 reductions. 83% of per-CU L2 BW — the 1-block/batch
// plateau. Multi-block needs agent fences that invalidate L2 (round-4:
// FETCH 7.8 MB -> 2.75 GB, 2.4x slower). Do NOT re-attempt without a
// fence-free exchange design.
__device__ __forceinline__ float bsum16(float v, float* red) {
    #pragma unroll
    for (int off = 32; off > 0; off >>= 1) v += __shfl_xor(v, off);
    __syncthreads();
    if ((threadIdx.x & 63) == 0) red[threadIdx.x >> 6] = v;
    __syncthreads();
    float s = 0.f;
    #pragma unroll
    for (int i = 0; i < 16; ++i) s += red[i];
    return s;
}

__global__ __launch_bounds__(1024) void rollout_k3(
    const float* __restrict__ Hs, const float* __restrict__ xpost,
    const float4* __restrict__ Wri4,          // [96*256]  (j4, o)
    const float* __restrict__ rib,
    const float4* __restrict__ Wih4,          // [64*768]  (j4, gate_o)
    const float4* __restrict__ Whh4,          // [64*768]
    const float* __restrict__ bih, const float* __restrict__ bhh,
    const float* __restrict__ lnw, const float* __restrict__ lnb,
    const float* __restrict__ rpw, const float* __restrict__ rpb,
    float* __restrict__ out)
{
    __shared__ __align__(16) float hc[384];    // h_r[0:256] ++ curr[256:384]
    __shared__ __align__(16) float zsh[256];
    __shared__ float zpart[4][256];
    __shared__ float gpart[6][4][256];
    __shared__ float red[16];

    const int tid = threadIdx.x;
    const int o = tid & 255, p = tid >> 8;
    const int b = blockIdx.x;

    if (p == 0) hc[o] = Hs[((size_t)b*QLEN + QLEN-1)*HH + o];
    if (p == 1 && o < DD) hc[HH + o] = xpost[b*DD + o];

    const float bi0 = bih[o],    bi1 = bih[HH+o], bi2 = bih[2*HH+o];
    const float bh0 = bhh[o],    bh1 = bhh[HH+o], bh2 = bhh[2*HH+o];
    const float rb  = rib[o];
    const float lw  = lnw[o],    lb  = lnb[o];
    const float rw0 = rpw[o],    rw1 = rpw[HH+o];
    const float rpb0 = rpb[0],   rpb1 = rpb[1];
    __syncthreads();

    for (int s = 0; s < WOUT; ++s) {
        // ---- z = tanh([h_r, curr] @ Wri^T + b): 384-dot split 4 ways (96 each)
        float az = 0.f;
        {
            const float4* wp = Wri4 + (size_t)(p*24)*256 + o;
            const float4* hp = reinterpret_cast<const float4*>(hc) + p*24;
            #pragma unroll 8
            for (int j4 = 0; j4 < 24; ++j4) {
                float4 w = wp[(size_t)j4*256];
                float4 h = hp[j4];
                az = fmaf(w.x, h.x, az); az = fmaf(w.y, h.y, az);
                az = fmaf(w.z, h.z, az); az = fmaf(w.w, h.w, az);
            }
        }
        zpart[p][o] = az;
        __syncthreads();
        if (p == 0)
            zsh[o] = tanhf(zpart[0][o]+zpart[1][o]+zpart[2][o]+zpart[3][o] + rb);
        __syncthreads();

        // ---- GRU gates: 6 dots of 256 split 4 ways (64 each)
        float g0=0.f,g1=0.f,g2=0.f,e0=0.f,e1=0.f,e2=0.f;
        {
            const float4* wip = Wih4 + (size_t)(p*16)*768 + o;
            const float4* whp = Whh4 + (size_t)(p*16)*768 + o;
            const float4* zp = reinterpret_cast<const float4*>(zsh) + p*16;
            const float4* hp = reinterpret_cast<const float4*>(hc)  + p*16;
            #pragma unroll 4
            for (int j4 = 0; j4 < 16; ++j4) {
                float4 z = zp[j4], h = hp[j4];
                float4 wa = wip[(size_t)j4*768];
                float4 wb = wip[(size_t)j4*768 + 256];
                float4 wc = wip[(size_t)j4*768 + 512];
                float4 wd = whp[(size_t)j4*768];
                float4 we = whp[(size_t)j4*768 + 256];
                float4 wf = whp[(size_t)j4*768 + 512];
                g0 = fmaf(wa.x,z.x,g0); g0 = fmaf(wa.y,z.y,g0); g0 = fmaf(wa.z,z.z,g0); g0 = fmaf(wa.w,z.w,g0);
                g1 = fmaf(wb.x,z.x,g1); g1 = fmaf(wb.y,z.y,g1); g1 = fmaf(wb.z,z.z,g1); g1 = fmaf(wb.w,z.w,g1);
                g2 = fmaf(wc.x,z.x,g2); g2 = fmaf(wc.y,z.y,g2); g2 = fmaf(wc.z,z.z,g2); g2 = fmaf(wc.w,z.w,g2);
                e0 = fmaf(wd.x,h.x,e0); e0 = fmaf(wd.y,h.y,e0); e0 = fmaf(wd.z,h.z,e0); e0 = fmaf(wd.w,h.w,e0);
                e1 = fmaf(we.x,h.x,e1); e1 = fmaf(we.y,h.y,e1); e1 = fmaf(we.z,h.z,e1); e1 = fmaf(we.w,h.w,e1);
                e2 = fmaf(wf.x,h.x,e2); e2 = fmaf(wf.y,h.y,e2); e2 = fmaf(wf.z,h.z,e2); e2 = fmaf(wf.w,h.w,e2);
            }
        }
        gpart[0][p][o]=g0; gpart[1][p][o]=g1; gpart[2][p][o]=g2;
        gpart[3][p][o]=e0; gpart[4][p][o]=e1; gpart[5][p][o]=e2;
        __syncthreads();

        float go = 0.f;
        if (p == 0) {
            float G0 = gpart[0][0][o]+gpart[0][1][o]+gpart[0][2][o]+gpart[0][3][o] + bi0;
            float G1 = gpart[1][0][o]+gpart[1][1][o]+gpart[1][2][o]+gpart[1][3][o] + bi1;
            float G2 = gpart[2][0][o]+gpart[2][1][o]+gpart[2][2][o]+gpart[2][3][o] + bi2;
            float E0 = gpart[3][0][o]+gpart[3][1][o]+gpart[3][2][o]+gpart[3][3][o] + bh0;
            float E1 = gpart[4][0][o]+gpart[4][1][o]+gpart[4][2][o]+gpart[4][3][o] + bh1;
            float E2 = gpart[5][0][o]+gpart[5][1][o]+gpart[5][2][o]+gpart[5][3][o] + bh2;
            float r  = sigmf(G0 + E0);
            float zg = sigmf(G1 + E1);
            float n  = tanhf(G2 + r*E2);
            go = (1.0f - zg)*n + zg*hc[o];
        }

        // ---- LN over 256 (non-p0 threads contribute zeros)
        float m   = bsum16(go, red) * (1.0f/HH);
        float d   = (p == 0) ? (go - m) : 0.f;
        float var = bsum16(d*d, red) * (1.0f/HH);
        float hn  = (p == 0) ? (d * rsqrtf(var + 1e-5f) * lw + lb) : 0.f;

        // ---- rp from new h_r
        float p0s = bsum16((p == 0) ? hn*rw0 : 0.f, red);
        float p1s = bsum16((p == 0) ? hn*rw1 : 0.f, red);
        float rho = 1.25f * sigmf(p0s + rpb0);
        float phi = PI_F * tanhf(p1s + rpb1);
        float sn, cs; sincosf(phi, &sn, &cs);

        if (p == 0) hc[o] = hn;
        if (tid < 64) {
            float cre = hc[HH + tid], cim = hc[HH + 64 + tid];
            float nr = rho*(cs*cre - sn*cim);
            float ni = rho*(sn*cre + cs*cim);
            hc[HH + tid] = nr; hc[HH + 64 + tid] = ni;
            float* ob = out + ((size_t)b*WOUT + s)*DD;
            ob[tid] = nr; ob[64 + tid] = ni;
        }
        __syncthreads();
    }
}

// ---------------------------------------------------------------------------
extern "C" void kernel_launch(void* const* d_in, const int* in_sizes, int n_in,
                              void* d_out, int out_size, void* d_ws, size_t ws_size,
                              hipStream_t stream)
{
    const float* x_in   = (const float*)d_in[0];
    const float* inp_w  = (const float*)d_in[2];
    const float* inp_b  = (const float*)d_in[3];
    const float* b0c1w  = (const float*)d_in[4];
    const float* b0c1b  = (const float*)d_in[5];
    const float* b0c2w  = (const float*)d_in[6];
    const float* b0c2b  = (const float*)d_in[7];
    const float* b0lnw  = (const float*)d_in[8];
    const float* b0lnb  = (const float*)d_in[9];
    const float* b1c1w  = (const float*)d_in[10];
    const float* b1c1b  = (const float*)d_in[11];
    const float* b1c2w  = (const float*)d_in[12];
    const float* b1c2b  = (const float*)d_in[13];
    const float* b1lnw  = (const float*)d_in[14];
    const float* b1lnb  = (const float*)d_in[15];
    const float* olnw   = (const float*)d_in[16];
    const float* olnb   = (const float*)d_in[17];
    const float* gainw  = (const float*)d_in[18];
    const float* gainb  = (const float*)d_in[19];
    const float* rpw    = (const float*)d_in[20];
    const float* rpb    = (const float*)d_in[21];
    const float* riw    = (const float*)d_in[22];
    const float* rib    = (const float*)d_in[23];
    const float* wih    = (const float*)d_in[24];
    const float* whh    = (const float*)d_in[25];
    const float* bih    = (const float*)d_in[26];
    const float* bhh    = (const float*)d_in[27];
    const float* rlnw   = (const float*)d_in[28];
    const float* rlnb   = (const float*)d_in[29];
    const float* rprw   = (const float*)d_in[30];
    const float* rprb   = (const float*)d_in[31];
    float* out = (float*)d_out;

    // workspace layout (floats)
    float* ws   = (float*)d_ws;
    float* buf0 = ws;                    // 8388608
    float* buf1 = ws +  8388608;         // 8388608
    float* buf2 = ws + 16777216;         // 8388608
    float* Kg    = buf2;                 // 4194304 (buf2 dead by then)
    float* rhoA  = buf2 + 4194304;       // 32768
    float* phiA  = rhoA + 32768;         // 32768
    float* xpost = phiA + 32768;         // 8192
    float* wts   = ws + 25165824;
    float* Wt_inp  = wts;                //  98304
    float* Wt_b0c1 = wts +   98304;      // 196608
    float* Wt_b0c2 = wts +  294912;      // 196608
    float* Wt_b1c1 = wts +  491520;      // 196608
    float* Wt_b1c2 = wts +  688128;      // 196608
    float* Wt_gain = wts +  884736;      //  32768
    float4* Wri4   = (float4*)(wts +  917504);   // 24576 float4 =  98304 floats
    float4* Wih4   = (float4*)(wts + 1015808);   // 49152 float4 = 196608 floats
    float4* Whh4   = (float4*)(wts + 1212416);   // 49152 float4 = 196608 floats
    // total ws use: 26574848 floats ~= 101.4 MB

    // ---- weight prep
    tconv_k<<<(98304+255)/256, 256, 0, stream>>>(inp_w, Wt_inp, 256, 384, 1);
    tconv_k<<<(196608+255)/256, 256, 0, stream>>>(b0c1w, Wt_b0c1, 256, 256, 3);
    tconv_k<<<(196608+255)/256, 256, 0, stream>>>(b0c2w, Wt_b0c2, 256, 256, 3);
    tconv_k<<<(196608+255)/256, 256, 0, stream>>>(b1c1w, Wt_b1c1, 256, 256, 3);
    tconv_k<<<(196608+255)/256, 256, 0, stream>>>(b1c2w, Wt_b1c2, 256, 256, 3);
    tconv_k<<<(32768+255)/256, 256, 0, stream>>>(gainw, Wt_gain, 128, 256, 1);
    pack_quads_k<<<(24576+255)/256, 256, 0, stream>>>(riw, Wri4, 256, 384);
    pack_quads_k<<<(49152+255)/256, 256, 0, stream>>>(wih, Wih4, 768, 256);
    pack_quads_k<<<(49152+255)/256, 256, 0, stream>>>(whh, Whh4, 768, 256);

    dim3 cg32(QLEN/32, NB);
    dim3 cg64(QLEN/64, NB);

    // ---- input projection (feats built on the fly): x_in -> buf0
    conv_gemm_k<384,256,1,1,0,1><<<cg32, 256, 0, stream>>>(x_in, Wt_inp, inp_b, buf0);

    // ---- block 0 (dil=1)
    conv64_k<256,256,3,1,1><<<cg64, 256, 0, stream>>>(buf0, Wt_b0c1, b0c1b, buf1);
    conv64_k<256,256,3,1,1><<<cg64, 256, 0, stream>>>(buf1, Wt_b0c2, b0c2b, buf2);
    ln_k<<<NB*QLEN/4, 256, 0, stream>>>(buf0, buf2, b0lnw, b0lnb, buf1);

    // ---- block 1 (dil=2)
    conv64_k<256,256,3,2,1><<<cg64, 256, 0, stream>>>(buf1, Wt_b1c1, b1c1b, buf0);
    conv64_k<256,256,3,2,1><<<cg64, 256, 0, stream>>>(buf0, Wt_b1c2, b1c2b, buf2);
    ln_k<<<NB*QLEN/4, 256, 0, stream>>>(buf1, buf2, b1lnw, b1lnb, buf0);

    // ---- output LN: h_seq -> buf1
    ln_k<<<NB*QLEN/4, 256, 0, stream>>>(buf0, nullptr, olnw, olnb, buf1);

    // ---- Kalman precompute: Kg (sigmoid GEMM), rho/phi
    conv_gemm_k<256,128,1,1,2,0><<<cg32, 256, 0, stream>>>(buf1, Wt_gain, gainb, Kg);
    rhophi_k<<<NB*QLEN/4, 256, 0, stream>>>(buf1, rpw, rpb, rhoA, phiA);

    // ---- Kalman scan
    kalman_k<<<NB, 64, 0, stream>>>(x_in, Kg, rhoA, phiA, xpost);

    // ---- rollout v3 (proven; fp32 precision-mandatory)
    rollout_k3<<<NB, 1024, 0, stream>>>(buf1, xpost, Wri4, rib, Wih4, Whh4,
                                        bih, bhh, rlnw, rlnb, rprw, rprb, out);
}

// Round 6
// 2153.098 us; speedup vs baseline: 1.7402x; 1.0976x over previous
//
#include <hip/hip_runtime.h>
#include <math.h>

#define QLEN 512
#define NB   64
#define DD   128
#define HH   256
#define WOUT 64
#define PI_F 3.14159265358979323846f

__device__ __forceinline__ float sigmf(float x){ return 1.0f/(1.0f+expf(-x)); }
__device__ __forceinline__ float geluf(float x){ return 0.5f*x*(1.0f+erff(x*0.7071067811865476f)); }

// ---------------------------------------------------------------------------
// Fused weight-prep: all transposes/packs in ONE launch (was 9 launches).
// tconv: (O,I,K) -> (K,I,O). pack_quads: (R,C) -> float4[j4*R + r].
// fp32 MANDATORY for rollout weights — recurrence amplifies weight noise ~1e6x
// (round-2 bf16: absmax 31 = fully decorrelated).
__device__ __forceinline__ void tconv_elem(const float* __restrict__ in,
                                           float* __restrict__ out,
                                           int idx, int O, int I, int K) {
    int o = idx % O; int rest = idx / O; int i = rest % I; int k = rest / I;
    out[idx] = in[(o*I + i)*K + k];
}
__device__ __forceinline__ void pq_elem(const float* __restrict__ in,
                                        float4* __restrict__ out,
                                        int idx, int R, int C) {
    int r = idx % R, j4 = idx / R;
    const float* p = in + (size_t)r*C + 4*j4;
    float4 v; v.x = p[0]; v.y = p[1]; v.z = p[2]; v.w = p[3];
    out[idx] = v;
}
__global__ __launch_bounds__(256) void prep_k(
    const float* __restrict__ inp_w, const float* __restrict__ b0c1w,
    const float* __restrict__ b0c2w, const float* __restrict__ b1c1w,
    const float* __restrict__ b1c2w, const float* __restrict__ gainw,
    const float* __restrict__ riw,  const float* __restrict__ wih,
    const float* __restrict__ whh,
    float* __restrict__ Wt_inp,  float* __restrict__ Wt_b0c1,
    float* __restrict__ Wt_b0c2, float* __restrict__ Wt_b1c1,
    float* __restrict__ Wt_b1c2, float* __restrict__ Wt_gain,
    float4* __restrict__ Wri4, float4* __restrict__ Wih4, float4* __restrict__ Whh4)
{
    int idx = blockIdx.x*256 + threadIdx.x;
    if      (idx <   98304) tconv_elem(inp_w, Wt_inp,  idx,          256, 384, 1);
    else if (idx <  294912) tconv_elem(b0c1w, Wt_b0c1, idx -  98304, 256, 256, 3);
    else if (idx <  491520) tconv_elem(b0c2w, Wt_b0c2, idx - 294912, 256, 256, 3);
    else if (idx <  688128) tconv_elem(b1c1w, Wt_b1c1, idx - 491520, 256, 256, 3);
    else if (idx <  884736) tconv_elem(b1c2w, Wt_b1c2, idx - 688128, 256, 256, 3);
    else if (idx <  917504) tconv_elem(gainw, Wt_gain, idx - 884736, 128, 256, 1);
    else if (idx <  942080) pq_elem(riw, Wri4, idx - 917504, 256, 384);
    else if (idx <  991232) pq_elem(wih, Wih4, idx - 942080, 768, 256);
    else if (idx < 1040384) pq_elem(whh, Whh4, idx - 991232, 768, 256);
}

// ---------------------------------------------------------------------------
// Conv-as-GEMM, TM=32 (round-3 proven config; TM=64 regressed ~180us in
// round 5 — 69.6 KB LDS halves occupancy). X rows (B,Q,CIN) time-major,
// Wt layout (KS,CIN,COUT). ACT: 0=none 1=gelu 2=sigmoid.
template<int CIN, int COUT, int KS, int DIL, int ACT, int FEATS>
__global__ __launch_bounds__(256) void conv_gemm_k(
    const float* __restrict__ X, const float* __restrict__ Wt,
    const float* __restrict__ bias, float* __restrict__ Y)
{
    constexpr int TM   = 32;
    constexpr int HALO = (KS == 3) ? DIL : 0;
    constexpr int ROWS = TM + 2*HALO;
    constexpr int CPT  = COUT/64;
    __shared__ __align__(16) float As[ROWS*CIN];

    const int b  = blockIdx.y;
    const int t0 = blockIdx.x * TM;
    const int tid = threadIdx.x;

    if constexpr (FEATS) {
        for (int idx = tid; idx < TM*DD; idx += 256) {
            int r = idx >> 7, d = idx & (DD-1);
            int t = t0 + r;
            const float* xr = X + ((size_t)b*QLEN + t)*DD + d;
            float x    = xr[0];
            float xm1  = (t >= 1) ? xr[-DD]   : 0.f;
            float xm2  = (t >= 2) ? xr[-2*DD] : 0.f;
            float dy   = (t >= 1) ? (x - xm1)   : 0.f;
            float dym1 = (t >= 2) ? (xm1 - xm2) : 0.f;
            float ddy  = (t >= 1) ? (dy - dym1) : 0.f;
            As[r*CIN + d]        = x;
            As[r*CIN + DD + d]   = dy;
            As[r*CIN + 2*DD + d] = ddy;
        }
    } else {
        for (int idx = tid; idx < ROWS*(CIN/4); idx += 256) {
            int r = idx / (CIN/4), c4 = idx % (CIN/4);
            int gr = t0 + r - HALO;
            gr = gr < 0 ? 0 : (gr > QLEN-1 ? QLEN-1 : gr);
            float4 v = reinterpret_cast<const float4*>(X + ((size_t)b*QLEN + gr)*CIN)[c4];
            reinterpret_cast<float4*>(As)[r*(CIN/4) + c4] = v;
        }
    }
    __syncthreads();

    const int lane = tid & 63, rg = tid >> 6;
    const int c0 = lane * CPT;
    const int r0 = rg * 8;

    float acc[8][CPT];
    #pragma unroll
    for (int j = 0; j < 8; ++j)
        #pragma unroll
        for (int p = 0; p < CPT; ++p) acc[j][p] = 0.f;

    for (int k = 0; k < KS; ++k) {
        const float* Wk = Wt + (size_t)k*CIN*COUT + c0;
        for (int ci = 0; ci < CIN; ci += 4) {
            float w[4][CPT];
            #pragma unroll
            for (int q = 0; q < 4; ++q) {
                if constexpr (CPT == 4) {
                    float4 wv = *reinterpret_cast<const float4*>(Wk + (size_t)(ci+q)*COUT);
                    w[q][0]=wv.x; w[q][1]=wv.y; w[q][2]=wv.z; w[q][3]=wv.w;
                } else {
                    float2 wv = *reinterpret_cast<const float2*>(Wk + (size_t)(ci+q)*COUT);
                    w[q][0]=wv.x; w[q][1]=wv.y;
                }
            }
            #pragma unroll
            for (int j = 0; j < 8; ++j) {
                const float4 a = *reinterpret_cast<const float4*>(&As[(r0 + j + k*DIL)*CIN + ci]);
                #pragma unroll
                for (int p = 0; p < CPT; ++p) {
                    acc[j][p] = fmaf(a.x, w[0][p], acc[j][p]);
                    acc[j][p] = fmaf(a.y, w[1][p], acc[j][p]);
                    acc[j][p] = fmaf(a.z, w[2][p], acc[j][p]);
                    acc[j][p] = fmaf(a.w, w[3][p], acc[j][p]);
                }
            }
        }
    }

    float bv[CPT];
    #pragma unroll
    for (int p = 0; p < CPT; ++p) bv[p] = bias[c0 + p];

    #pragma unroll
    for (int j = 0; j < 8; ++j) {
        float o[CPT];
        #pragma unroll
        for (int p = 0; p < CPT; ++p) {
            float v = acc[j][p] + bv[p];
            if constexpr (ACT == 1) v = geluf(v);
            if constexpr (ACT == 2) v = sigmf(v);
            o[p] = v;
        }
        float* yr = Y + ((size_t)b*QLEN + t0 + r0 + j)*COUT + c0;
        if constexpr (CPT == 4) {
            float4 ov; ov.x=o[0]; ov.y=o[1]; ov.z=o[2]; ov.w=o[3];
            *reinterpret_cast<float4*>(yr) = ov;
        } else {
            float2 ov; ov.x=o[0]; ov.y=o[1];
            *reinterpret_cast<float2*>(yr) = ov;
        }
    }
}

// ---------------------------------------------------------------------------
// LayerNorm over H=256 per (b,t) row with residual add.
__global__ __launch_bounds__(256) void ln_k(
    const float* __restrict__ X, const float* __restrict__ R,
    const float* __restrict__ w, const float* __restrict__ b,
    float* __restrict__ Y)
{
    int row  = blockIdx.x*4 + (threadIdx.x >> 6);
    int lane = threadIdx.x & 63;
    float4 v = reinterpret_cast<const float4*>(X + (size_t)row*HH)[lane];
    float4 rv = reinterpret_cast<const float4*>(R + (size_t)row*HH)[lane];
    v.x += rv.x; v.y += rv.y; v.z += rv.z; v.w += rv.w;
    float s = v.x + v.y + v.z + v.w;
    #pragma unroll
    for (int off = 32; off > 0; off >>= 1) s += __shfl_xor(s, off);
    float m = s * (1.0f/HH);
    float dx=v.x-m, dy=v.y-m, dz=v.z-m, dw=v.w-m;
    float q = dx*dx + dy*dy + dz*dz + dw*dw;
    #pragma unroll
    for (int off = 32; off > 0; off >>= 1) q += __shfl_xor(q, off);
    float inv = rsqrtf(q*(1.0f/HH) + 1e-5f);
    float4 wv = reinterpret_cast<const float4*>(w)[lane];
    float4 bv = reinterpret_cast<const float4*>(b)[lane];
    float4 o;
    o.x = dx*inv*wv.x + bv.x;
    o.y = dy*inv*wv.y + bv.y;
    o.z = dz*inv*wv.z + bv.z;
    o.w = dw*inv*wv.w + bv.w;
    reinterpret_cast<float4*>(Y + (size_t)row*HH)[lane] = o;
}

// ---------------------------------------------------------------------------
// Fused output-LN + rho/phi (was ln_k + rhophi_k: saves a 33 MB pass).
__global__ __launch_bounds__(256) void ln_rp_k(
    const float* __restrict__ X, const float* __restrict__ w, const float* __restrict__ b,
    const float* __restrict__ rpw, const float* __restrict__ rpb,
    float* __restrict__ Y, float* __restrict__ rho, float* __restrict__ phi)
{
    int row  = blockIdx.x*4 + (threadIdx.x >> 6);
    int lane = threadIdx.x & 63;
    float4 v = reinterpret_cast<const float4*>(X + (size_t)row*HH)[lane];
    float s = v.x + v.y + v.z + v.w;
    #pragma unroll
    for (int off = 32; off > 0; off >>= 1) s += __shfl_xor(s, off);
    float m = s * (1.0f/HH);
    float dx=v.x-m, dy=v.y-m, dz=v.z-m, dw=v.w-m;
    float q = dx*dx + dy*dy + dz*dz + dw*dw;
    #pragma unroll
    for (int off = 32; off > 0; off >>= 1) q += __shfl_xor(q, off);
    float inv = rsqrtf(q*(1.0f/HH) + 1e-5f);
    float4 wv = reinterpret_cast<const float4*>(w)[lane];
    float4 bv = reinterpret_cast<const float4*>(b)[lane];
    float4 o;
    o.x = dx*inv*wv.x + bv.x;
    o.y = dy*inv*wv.y + bv.y;
    o.z = dz*inv*wv.z + bv.z;
    o.w = dw*inv*wv.w + bv.w;
    reinterpret_cast<float4*>(Y + (size_t)row*HH)[lane] = o;

    float4 w0 = reinterpret_cast<const float4*>(rpw)[lane];
    float4 w1 = reinterpret_cast<const float4*>(rpw + HH)[lane];
    float d0 = o.x*w0.x + o.y*w0.y + o.z*w0.z + o.w*w0.w;
    float d1 = o.x*w1.x + o.y*w1.y + o.z*w1.z + o.w*w1.w;
    #pragma unroll
    for (int off = 32; off > 0; off >>= 1) { d0 += __shfl_xor(d0, off); d1 += __shfl_xor(d1, off); }
    if (lane == 0) {
        rho[row] = 1.25f * sigmf(d0 + rpb[0]);
        phi[row] = PI_F * tanhf(d1 + rpb[1]);
    }
}

// ---------------------------------------------------------------------------
// Kalman scan with next-step prefetch (hides ~200cyc L2 latency per step).
__global__ __launch_bounds__(64) void kalman_k(
    const float* __restrict__ Xin, const float* __restrict__ Kg,
    const float* __restrict__ rho_a, const float* __restrict__ phi_a,
    float* __restrict__ xpost)
{
    int b = blockIdx.x, l = threadIdx.x;
    const float* xb = Xin + (size_t)b*QLEN*DD;
    float re = xb[l], im = xb[64 + l];

    float rho_c = rho_a[b*QLEN], phi_c = phi_a[b*QLEN];
    const float* kg0 = Kg + (size_t)b*QLEN*DD;
    float kr_c = kg0[l], ki_c = kg0[64 + l];
    float y0_c = xb[l],  y1_c = xb[64 + l];

    for (int t = 0; t < QLEN; ++t) {
        float rho_n = 0.f, phi_n = 0.f, kr_n = 0.f, ki_n = 0.f, y0_n = 0.f, y1_n = 0.f;
        if (t + 1 < QLEN) {
            rho_n = rho_a[b*QLEN + t + 1];
            phi_n = phi_a[b*QLEN + t + 1];
            const float* kg = Kg + ((size_t)b*QLEN + t + 1)*DD;
            const float* yr = xb + (size_t)(t + 1)*DD;
            kr_n = kg[l]; ki_n = kg[64 + l];
            y0_n = yr[l]; y1_n = yr[64 + l];
        }
        float sn, cs; sincosf(phi_c, &sn, &cs);
        float pr = rho_c*(cs*re - sn*im);
        float pi = rho_c*(sn*re + cs*im);
        re = pr + kr_c*(y0_c - pr);
        im = pi + ki_c*(y1_c - pi);
        rho_c = rho_n; phi_c = phi_n; kr_c = kr_n; ki_c = ki_n; y0_c = y0_n; y1_c = y1_n;
    }
    xpost[b*DD + l]      = re;
    xpost[b*DD + 64 + l] = im;
}

// ---------------------------------------------------------------------------
// Rollout v5: one block/batch, 1024 threads, fp32 weights (precision-
// mandatory). Phase A streams Wri + Whh (1.18 MB, both depend only on h)
// before the z barrier; phase B streams Wih (786 KB). Structural floor:
// 1.97 MB/step thru one CU's L2 port (~144 GB/s) = 876 us. Multi-block
// variants need agent fences that invalidate L2 (round 4: FETCH 7.8MB ->
// 2.75GB, 2.4x slower) — do not re-attempt.
__device__ __forceinline__ float bsum16(float v, float* red) {
    #pragma unroll
    for (int off = 32; off > 0; off >>= 1) v += __shfl_xor(v, off);
    __syncthreads();
    if ((threadIdx.x & 63) == 0) red[threadIdx.x >> 6] = v;
    __syncthreads();
    float s = 0.f;
    #pragma unroll
    for (int i = 0; i < 16; ++i) s += red[i];
    return s;
}
__device__ __forceinline__ float2 bsum16_2(float a, float b, float* red) {
    #pragma unroll
    for (int off = 32; off > 0; off >>= 1) { a += __shfl_xor(a, off); b += __shfl_xor(b, off); }
    __syncthreads();
    if ((threadIdx.x & 63) == 0) { red[threadIdx.x >> 6] = a; red[16 + (threadIdx.x >> 6)] = b; }
    __syncthreads();
    float sa = 0.f, sb = 0.f;
    #pragma unroll
    for (int i = 0; i < 16; ++i) { sa += red[i]; sb += red[16 + i]; }
    float2 r; r.x = sa; r.y = sb; return r;
}

__global__ __launch_bounds__(1024) void rollout_k5(
    const float* __restrict__ Hs, const float* __restrict__ xpost,
    const float4* __restrict__ Wri4,          // [96*256]  (j4, o)
    const float* __restrict__ rib,
    const float4* __restrict__ Wih4,          // [64*768]  (j4, gate_o)
    const float4* __restrict__ Whh4,          // [64*768]
    const float* __restrict__ bih, const float* __restrict__ bhh,
    const float* __restrict__ lnw, const float* __restrict__ lnb,
    const float* __restrict__ rpw, const float* __restrict__ rpb,
    float* __restrict__ out)
{
    __shared__ __align__(16) float hc[384];    // h_r[0:256] ++ curr[256:384]
    __shared__ __align__(16) float zsh[256];
    __shared__ float zpart[4][256];
    __shared__ float gpart[6][4][256];
    __shared__ float red[32];

    const int tid = threadIdx.x;
    const int o = tid & 255, p = tid >> 8;
    const int b = blockIdx.x;

    if (p == 0) hc[o] = Hs[((size_t)b*QLEN + QLEN-1)*HH + o];
    if (p == 1 && o < DD) hc[HH + o] = xpost[b*DD + o];

    const float bi0 = bih[o],    bi1 = bih[HH+o], bi2 = bih[2*HH+o];
    const float bh0 = bhh[o],    bh1 = bhh[HH+o], bh2 = bhh[2*HH+o];
    const float rb  = rib[o];
    const float lw  = lnw[o],    lb  = lnb[o];
    const float rw0 = rpw[o],    rw1 = rpw[HH+o];
    const float rpb0 = rpb[0],   rpb1 = rpb[1];
    const float4* hc4 = reinterpret_cast<const float4*>(hc);
    const float4* zf4 = reinterpret_cast<const float4*>(zsh);
    __syncthreads();

    for (int s = 0; s < WOUT; ++s) {
        // ---- Phase A: z-partials (Wri, 96 dims) + e-partials (Whh, 64 dims)
        float az = 0.f;
        {
            const float4* wp = Wri4 + (size_t)(p*24)*256 + o;
            #pragma unroll 8
            for (int j4 = 0; j4 < 24; ++j4) {
                float4 w = wp[(size_t)j4*256];
                float4 h = hc4[p*24 + j4];
                az = fmaf(w.x, h.x, az); az = fmaf(w.y, h.y, az);
                az = fmaf(w.z, h.z, az); az = fmaf(w.w, h.w, az);
            }
        }
        float e0=0.f, e1=0.f, e2=0.f;
        {
            const float4* whp = Whh4 + (size_t)(p*16)*768 + o;
            #pragma unroll 4
            for (int j4 = 0; j4 < 16; ++j4) {
                float4 h = hc4[p*4 + (j4>>2)*16 + (j4&3)];   // == hc4[p*16+j4] reordered? no:
                h = hc4[p*16 + j4];
                float4 wd = whp[(size_t)j4*768];
                float4 we = whp[(size_t)j4*768 + 256];
                float4 wf = whp[(size_t)j4*768 + 512];
                e0 = fmaf(wd.x,h.x,e0); e0 = fmaf(wd.y,h.y,e0); e0 = fmaf(wd.z,h.z,e0); e0 = fmaf(wd.w,h.w,e0);
                e1 = fmaf(we.x,h.x,e1); e1 = fmaf(we.y,h.y,e1); e1 = fmaf(we.z,h.z,e1); e1 = fmaf(we.w,h.w,e1);
                e2 = fmaf(wf.x,h.x,e2); e2 = fmaf(wf.y,h.y,e2); e2 = fmaf(wf.z,h.z,e2); e2 = fmaf(wf.w,h.w,e2);
            }
        }
        zpart[p][o] = az;
        gpart[3][p][o]=e0; gpart[4][p][o]=e1; gpart[5][p][o]=e2;
        __syncthreads();
        if (p == 0)
            zsh[o] = tanhf(zpart[0][o]+zpart[1][o]+zpart[2][o]+zpart[3][o] + rb);
        __syncthreads();

        // ---- Phase B: g-partials (Wih, 64 dims each)
        float g0=0.f, g1=0.f, g2=0.f;
        {
            const float4* wip = Wih4 + (size_t)(p*16)*768 + o;
            #pragma unroll 4
            for (int j4 = 0; j4 < 16; ++j4) {
                float4 z = zf4[p*16 + j4];
                float4 wa = wip[(size_t)j4*768];
                float4 wb = wip[(size_t)j4*768 + 256];
                float4 wc = wip[(size_t)j4*768 + 512];
                g0 = fmaf(wa.x,z.x,g0); g0 = fmaf(wa.y,z.y,g0); g0 = fmaf(wa.z,z.z,g0); g0 = fmaf(wa.w,z.w,g0);
                g1 = fmaf(wb.x,z.x,g1); g1 = fmaf(wb.y,z.y,g1); g1 = fmaf(wb.z,z.z,g1); g1 = fmaf(wb.w,z.w,g1);
                g2 = fmaf(wc.x,z.x,g2); g2 = fmaf(wc.y,z.y,g2); g2 = fmaf(wc.z,z.z,g2); g2 = fmaf(wc.w,z.w,g2);
            }
        }
        gpart[0][p][o]=g0; gpart[1][p][o]=g1; gpart[2][p][o]=g2;
        __syncthreads();

        float go = 0.f;
        if (p == 0) {
            float G0 = gpart[0][0][o]+gpart[0][1][o]+gpart[0][2][o]+gpart[0][3][o] + bi0;
            float G1 = gpart[1][0][o]+gpart[1][1][o]+gpart[1][2][o]+gpart[1][3][o] + bi1;
            float G2 = gpart[2][0][o]+gpart[2][1][o]+gpart[2][2][o]+gpart[2][3][o] + bi2;
            float E0 = gpart[3][0][o]+gpart[3][1][o]+gpart[3][2][o]+gpart[3][3][o] + bh0;
            float E1 = gpart[4][0][o]+gpart[4][1][o]+gpart[4][2][o]+gpart[4][3][o] + bh1;
            float E2 = gpart[5][0][o]+gpart[5][1][o]+gpart[5][2][o]+gpart[5][3][o] + bh2;
            float r  = sigmf(G0 + E0);
            float zg = sigmf(G1 + E1);
            float n  = tanhf(G2 + r*E2);
            go = (1.0f - zg)*n + zg*hc[o];
        }

        // ---- LN over 256 (two-pass, matches reference order)
        float m   = bsum16(go, red) * (1.0f/HH);
        float d   = (p == 0) ? (go - m) : 0.f;
        float var = bsum16(d*d, red) * (1.0f/HH);
        float hn  = (p == 0) ? (d * rsqrtf(var + 1e-5f) * lw + lb) : 0.f;

        // ---- rho/phi: fused dual reduction
        float2 ps = bsum16_2((p == 0) ? hn*rw0 : 0.f, (p == 0) ? hn*rw1 : 0.f, red);
        float rho = 1.25f * sigmf(ps.x + rpb0);
        float phi = PI_F * tanhf(ps.y + rpb1);
        float sn, cs; sincosf(phi, &sn, &cs);

        if (p == 0) hc[o] = hn;
        if (tid < 64) {
            float cre = hc[HH + tid], cim = hc[HH + 64 + tid];
            float nr = rho*(cs*cre - sn*cim);
            float ni = rho*(sn*cre + cs*cim);
            hc[HH + tid] = nr; hc[HH + 64 + tid] = ni;
            float* ob = out + ((size_t)b*WOUT + s)*DD;
            ob[tid] = nr; ob[64 + tid] = ni;
        }
        __syncthreads();
    }
}

// ---------------------------------------------------------------------------
extern "C" void kernel_launch(void* const* d_in, const int* in_sizes, int n_in,
                              void* d_out, int out_size, void* d_ws, size_t ws_size,
                              hipStream_t stream)
{
    const float* x_in   = (const float*)d_in[0];
    const float* inp_w  = (const float*)d_in[2];
    const float* inp_b  = (const float*)d_in[3];
    const float* b0c1w  = (const float*)d_in[4];
    const float* b0c1b  = (const float*)d_in[5];
    const float* b0c2w  = (const float*)d_in[6];
    const float* b0c2b  = (const float*)d_in[7];
    const float* b0lnw  = (const float*)d_in[8];
    const float* b0lnb  = (const float*)d_in[9];
    const float* b1c1w  = (const float*)d_in[10];
    const float* b1c1b  = (const float*)d_in[11];
    const float* b1c2w  = (const float*)d_in[12];
    const float* b1c2b  = (const float*)d_in[13];
    const float* b1lnw  = (const float*)d_in[14];
    const float* b1lnb  = (const float*)d_in[15];
    const float* olnw   = (const float*)d_in[16];
    const float* olnb   = (const float*)d_in[17];
    const float* gainw  = (const float*)d_in[18];
    const float* gainb  = (const float*)d_in[19];
    const float* rpw    = (const float*)d_in[20];
    const float* rpb    = (const float*)d_in[21];
    const float* riw    = (const float*)d_in[22];
    const float* rib    = (const float*)d_in[23];
    const float* wih    = (const float*)d_in[24];
    const float* whh    = (const float*)d_in[25];
    const float* bih    = (const float*)d_in[26];
    const float* bhh    = (const float*)d_in[27];
    const float* rlnw   = (const float*)d_in[28];
    const float* rlnb   = (const float*)d_in[29];
    const float* rprw   = (const float*)d_in[30];
    const float* rprb   = (const float*)d_in[31];
    float* out = (float*)d_out;

    // workspace layout (floats)
    float* ws   = (float*)d_ws;
    float* buf0 = ws;                    // 8388608
    float* buf1 = ws +  8388608;         // 8388608
    float* buf2 = ws + 16777216;         // 8388608
    float* Kg    = buf2;                 // 4194304 (buf2 dead by then)
    float* rhoA  = buf2 + 4194304;       // 32768
    float* phiA  = rhoA + 32768;         // 32768
    float* xpost = phiA + 32768;         // 8192
    float* wts   = ws + 25165824;
    float* Wt_inp  = wts;                //  98304
    float* Wt_b0c1 = wts +   98304;      // 196608
    float* Wt_b0c2 = wts +  294912;      // 196608
    float* Wt_b1c1 = wts +  491520;      // 196608
    float* Wt_b1c2 = wts +  688128;      // 196608
    float* Wt_gain = wts +  884736;      //  32768
    float4* Wri4   = (float4*)(wts +  917504);   // 24576 float4
    float4* Wih4   = (float4*)(wts + 1015808);   // 49152 float4
    float4* Whh4   = (float4*)(wts + 1212416);   // 49152 float4
    // total ws use: 26574848 floats ~= 101.4 MB

    // ---- fused weight prep (1 launch, was 9)
    prep_k<<<4064, 256, 0, stream>>>(inp_w, b0c1w, b0c2w, b1c1w, b1c2w, gainw,
                                     riw, wih, whh,
                                     Wt_inp, Wt_b0c1, Wt_b0c2, Wt_b1c1, Wt_b1c2,
                                     Wt_gain, Wri4, Wih4, Whh4);

    dim3 cg32(QLEN/32, NB);

    // ---- input projection (feats built on the fly): x_in -> buf0
    conv_gemm_k<384,256,1,1,0,1><<<cg32, 256, 0, stream>>>(x_in, Wt_inp, inp_b, buf0);

    // ---- block 0 (dil=1)
    conv_gemm_k<256,256,3,1,1,0><<<cg32, 256, 0, stream>>>(buf0, Wt_b0c1, b0c1b, buf1);
    conv_gemm_k<256,256,3,1,1,0><<<cg32, 256, 0, stream>>>(buf1, Wt_b0c2, b0c2b, buf2);
    ln_k<<<NB*QLEN/4, 256, 0, stream>>>(buf0, buf2, b0lnw, b0lnb, buf1);

    // ---- block 1 (dil=2)
    conv_gemm_k<256,256,3,2,1,0><<<cg32, 256, 0, stream>>>(buf1, Wt_b1c1, b1c1b, buf0);
    conv_gemm_k<256,256,3,2,1,0><<<cg32, 256, 0, stream>>>(buf0, Wt_b1c2, b1c2b, buf2);
    ln_k<<<NB*QLEN/4, 256, 0, stream>>>(buf1, buf2, b1lnw, b1lnb, buf0);

    // ---- fused output LN + rho/phi: buf0 -> buf1, rhoA, phiA
    ln_rp_k<<<NB*QLEN/4, 256, 0, stream>>>(buf0, olnw, olnb, rpw, rpb,
                                           buf1, rhoA, phiA);

    // ---- Kg (sigmoid GEMM)
    conv_gemm_k<256,128,1,1,2,0><<<cg32, 256, 0, stream>>>(buf1, Wt_gain, gainb, Kg);

    // ---- Kalman scan (prefetch-pipelined)
    kalman_k<<<NB, 64, 0, stream>>>(x_in, Kg, rhoA, phiA, xpost);

    // ---- rollout v5 (fp32 precision-mandatory)
    rollout_k5<<<NB, 1024, 0, stream>>>(buf1, xpost, Wri4, rib, Wih4, Whh4,
                                        bih, bhh, rlnw, rlnb, rprw, rprb, out);
}